// Round 1
// baseline (30.902 us; speedup 1.0000x reference)
//
#include <hip/hip_runtime.h>

// out[b,c,m] = max_n x[b,c,n] * Bt[m,n],  Bt binary {0,1}, ~3 ones / row.
// Exact sparse formulation:
//   row has a zero (always in practice) -> out = max(0, max over ones of x)
//   row all ones (never in practice)    -> out = max over all n of x  (fallback kernel)
// Positive floats compare correctly as uint bit patterns -> atomicMax on bits,
// with out pre-zeroed (0 bits == 0.0f == the clamp). Non-positive x skipped.

#define HG_N_IN   2048
#define HG_N_OUT  4096
#define HG_BC     32      // BATCH * FEAT = 2*16

__global__ void hg_scan_emit(const float4* __restrict__ Bt4,
                             const float* __restrict__ x,
                             unsigned int* __restrict__ outBits,
                             int* __restrict__ counts,
                             int totalVec) {
    const int stride = gridDim.x * blockDim.x;
    const int lane = threadIdx.x & 63;
    for (int i = blockIdx.x * blockDim.x + threadIdx.x; i < totalVec; i += stride) {
        float4 v = Bt4[i];
        int e  = i << 2;
        int m  = e >> 11;              // / N_IN
        int n0 = e & (HG_N_IN - 1);
        int f0 = (v.x != 0.0f), f1 = (v.y != 0.0f);
        int f2 = (v.z != 0.0f), f3 = (v.w != 0.0f);
        int cnt = f0 + f1 + f2 + f3;
        // wave-uniform early out (ballot is wave-wide, no divergence here)
        unsigned long long anyb = __ballot(cnt != 0);
        if (anyb == 0ull) continue;
        if (cnt && counts) atomicAdd(&counts[m], cnt);   // all-ones-row detection
        #pragma unroll
        for (int j = 0; j < 4; ++j) {
            int flag = (j == 0) ? f0 : (j == 1) ? f1 : (j == 2) ? f2 : f3;
            unsigned long long b = __ballot(flag);
            while (b) {
                int src = __ffsll(b) - 1;
                b &= b - 1;
                int n  = __shfl(n0 + j, src);
                int mm = __shfl(m, src);
                if (lane < HG_BC) {
                    float xv = x[lane * HG_N_IN + n];
                    if (xv > 0.0f) {
                        atomicMax(&outBits[lane * HG_N_OUT + mm], __float_as_uint(xv));
                    }
                }
            }
        }
    }
}

// Exact fallback for all-ones rows (no zero term -> no clamp at 0).
// counts[m] == N_IN is astronomically improbable for this data; this never runs.
__global__ void hg_fallback_allones(const float* __restrict__ x,
                                    const int* __restrict__ counts,
                                    float* __restrict__ out) {
    int m = blockIdx.x * blockDim.x + threadIdx.x;
    if (m >= HG_N_OUT) return;
    if (counts[m] != HG_N_IN) return;
    for (int bc = 0; bc < HG_BC; ++bc) {
        float mx = -INFINITY;
        for (int n = 0; n < HG_N_IN; ++n) mx = fmaxf(mx, x[bc * HG_N_IN + n]);
        out[bc * HG_N_OUT + m] = mx;
    }
}

extern "C" void kernel_launch(void* const* d_in, const int* in_sizes, int n_in,
                              void* d_out, int out_size, void* d_ws, size_t ws_size,
                              hipStream_t stream) {
    const float* x  = (const float*)d_in[0];                 // [2,16,2048] f32
    const float4* Bt4 = (const float4*)d_in[1];              // [4096,2048] f32 as float4
    float* out = (float*)d_out;                              // [2,16,4096] f32
    unsigned int* outBits = (unsigned int*)d_out;

    const bool have_ws = (ws_size >= HG_N_OUT * sizeof(int));
    int* counts = have_ws ? (int*)d_ws : nullptr;

    // init: out = 0.0f (bits 0), counts = 0  (must happen every call)
    hipMemsetAsync(d_out, 0, (size_t)out_size * sizeof(float), stream);
    if (have_ws) hipMemsetAsync(d_ws, 0, HG_N_OUT * sizeof(int), stream);

    const int totalVec = (HG_N_OUT * HG_N_IN) / 4;           // 2,097,152 float4s
    hg_scan_emit<<<2048, 256, 0, stream>>>(Bt4, x, outBits, counts, totalVec);
    if (have_ws) {
        hg_fallback_allones<<<(HG_N_OUT + 255) / 256, 256, 0, stream>>>(x, counts, out);
    }
}